// Round 9
// baseline (186.573 us; speedup 1.0000x reference)
//
#include <hip/hip_runtime.h>
#include <stdint.h>

#define S_LEN 2048
#define D_MODEL 1024
#define NH 16
#define DKV 64

typedef unsigned short u16;
typedef __bf16 bf16x8 __attribute__((ext_vector_type(8)));
typedef float f32x4 __attribute__((ext_vector_type(4)));
typedef float f32x16 __attribute__((ext_vector_type(16)));

__device__ __forceinline__ u16 f2bf(float f) {
  union { float f; uint32_t u; } v; v.f = f;
  uint32_t r = v.u + 0x7FFFu + ((v.u >> 16) & 1u);
  return (u16)(r >> 16);
}
// pack two positive floats to bf16x2: round-half-up + single v_perm
__device__ __forceinline__ uint32_t pkbf2(float lo, float hi) {
  union { float f; uint32_t u; } a, b; a.f = hi; b.f = lo;
  return __builtin_amdgcn_perm(a.u + 0x8000u, b.u + 0x8000u, 0x07060302u);
}
// async global->LDS 16B: lds dest is WAVE-UNIFORM base; HW adds lane*16
__device__ __forceinline__ void gl16(const u16* g, u16* l) {
  __builtin_amdgcn_global_load_lds(
      (const __attribute__((address_space(1))) unsigned int*)g,
      (__attribute__((address_space(3))) unsigned int*)l, 16, 0, 0);
}

// ---------- fused preprocessing: conv QKV + transpose Wq/Wk/Wv + transpose Wo ----------
__global__ __launch_bounds__(256) void prep_k(
    const float* __restrict__ Q, const float* __restrict__ K,
    const float* __restrict__ V, const float* __restrict__ Wq,
    const float* __restrict__ Wk, const float* __restrict__ Wv,
    const float* __restrict__ Wo, u16* __restrict__ QKVb,
    u16* __restrict__ Wqt, u16* __restrict__ Wkt, u16* __restrict__ Wvt,
    u16* __restrict__ Wot) {
  __shared__ float tile[32][33];
  const int idx = blockIdx.x;
  if (idx < 6144) {
    const int z = idx >> 11, blk = idx & 2047;
    const float* src = (z == 0) ? Q : (z == 1) ? K : V;
    u16* dst = QKVb + (size_t)z * S_LEN * D_MODEL;
    size_t i = ((size_t)blk * 256 + threadIdx.x) * 4;
    const float4 v = *(const float4*)(src + i);
    union { u16 h[4]; uint2 u2; } o;
    o.h[0] = f2bf(v.x); o.h[1] = f2bf(v.y); o.h[2] = f2bf(v.z); o.h[3] = f2bf(v.w);
    *(uint2*)(dst + i) = o.u2;
    return;
  }
  const float* ip; u16* op; int R, C, r0, c0;
  if (idx < 9216) {
    int t = idx - 6144;
    int which = t >> 10, head = (t & 1023) >> 6, tl = t & 63;
    ip = ((which == 0) ? Wq : (which == 1) ? Wk : Wv) + (size_t)head * D_MODEL * DKV;
    op = ((which == 0) ? Wqt : (which == 1) ? Wkt : Wvt) + (size_t)head * D_MODEL * DKV;
    R = D_MODEL; C = DKV; c0 = (tl & 1) * 32; r0 = (tl >> 1) * 32;
  } else {
    int t = idx - 9216;
    ip = Wo; op = Wot; R = D_MODEL; C = D_MODEL;
    c0 = (t & 31) * 32; r0 = (t >> 5) * 32;
  }
  int tr = threadIdx.x >> 5, tc = threadIdx.x & 31;
#pragma unroll
  for (int i = 0; i < 4; i++)
    tile[tr + i * 8][tc] = ip[(size_t)(r0 + tr + i * 8) * C + c0 + tc];
  __syncthreads();
#pragma unroll
  for (int i = 0; i < 4; i++) {
    int c = tr + i * 8;
    op[(size_t)(c0 + c) * R + r0 + tc] = f2bf(tile[tc][c]);
  }
}

// ---------- projection GEMM m97-style: 128x128 tile, BK=64, async dbuf, 1 barrier/iter ----------
__global__ __launch_bounds__(256, 2) void proj_gemm_k(
    const u16* __restrict__ qkvb, const u16* __restrict__ Wqt,
    const u16* __restrict__ Wkt, const u16* __restrict__ Wvt,
    const float* __restrict__ bq, const float* __restrict__ bk,
    const float* __restrict__ bv,
    u16* __restrict__ qb, u16* __restrict__ kb, u16* __restrict__ vT) {
  const int z = blockIdx.z;
  const int m0 = blockIdx.x * 128, n0 = blockIdx.y * 128;
  const u16* A = qkvb + (size_t)z * S_LEN * D_MODEL;
  const u16* Bt = (z == 0) ? Wqt : (z == 1) ? Wkt : Wvt;
  const float* bias = (z == 0) ? bq : (z == 1) ? bk : bv;
  const float scale = (z == 0) ? 0.18033688f : 1.0f;  // (1/8)*log2(e) folded into q

  __shared__ __align__(16) u16 smem[4 * 8192];
  const int tid = threadIdx.x;
  const int w = tid >> 6, lane = tid & 63, quad = lane >> 4, l15 = lane & 15;
  const int wm = (w >> 1) * 64, wn = (w & 1) * 64;
  const int pb = w * 256;

  f32x4 acc[4][4] = {};

  {
    u16* As = smem; u16* Bs = smem + 16384;
#pragma unroll
    for (int e = 0; e < 4; e++) {
      int p = pb + e * 64 + lane;
      int r = p >> 3, cg = (p & 7) ^ (r & 7);
      gl16(&A[(size_t)(m0 + r) * D_MODEL + cg * 8], As + (pb + e * 64) * 8);
      gl16(&Bt[(size_t)(n0 + r) * D_MODEL + cg * 8], Bs + (pb + e * 64) * 8);
    }
  }
  for (int it = 0; it < 16; it++) {
    __syncthreads();
    if (it < 15) {
      const int k0 = (it + 1) * 64;
      u16* As = smem + ((it + 1) & 1) * 8192;
      u16* Bs = smem + 16384 + ((it + 1) & 1) * 8192;
#pragma unroll
      for (int e = 0; e < 4; e++) {
        int p = pb + e * 64 + lane;
        int r = p >> 3, cg = (p & 7) ^ (r & 7);
        gl16(&A[(size_t)(m0 + r) * D_MODEL + k0 + cg * 8], As + (pb + e * 64) * 8);
        gl16(&Bt[(size_t)(n0 + r) * D_MODEL + k0 + cg * 8], Bs + (pb + e * 64) * 8);
      }
    }
    const u16* As = smem + (it & 1) * 8192;
    const u16* Bs = smem + 16384 + (it & 1) * 8192;
#pragma unroll
    for (int kc = 0; kc < 2; kc++) {
      bf16x8 af[4], bfr[4];
      const int c = kc * 4 + quad;
#pragma unroll
      for (int t = 0; t < 4; t++) {
        int ma = wm + t * 16 + l15, na = wn + t * 16 + l15;
        af[t] = *(const bf16x8*)&As[(ma * 8 + (c ^ (ma & 7))) * 8];
        bfr[t] = *(const bf16x8*)&Bs[(na * 8 + (c ^ (na & 7))) * 8];
      }
#pragma unroll
      for (int tm = 0; tm < 4; tm++)
#pragma unroll
        for (int tn = 0; tn < 4; tn++)
          acc[tm][tn] = __builtin_amdgcn_mfma_f32_16x16x32_bf16(af[tm], bfr[tn], acc[tm][tn], 0, 0, 0);
    }
  }

  if (z < 2) {
    u16* O = (z == 0) ? qb : kb;
#pragma unroll
    for (int tm = 0; tm < 4; tm++)
#pragma unroll
      for (int tn = 0; tn < 4; tn++)
#pragma unroll
        for (int r = 0; r < 4; r++) {
          int row = m0 + wm + tm * 16 + quad * 4 + r;
          int col = n0 + wn + tn * 16 + l15;
          O[(size_t)row * D_MODEL + col] = f2bf((acc[tm][tn][r] + bias[col]) * scale);
        }
  } else {
#pragma unroll
    for (int tm = 0; tm < 4; tm++)
#pragma unroll
      for (int tn = 0; tn < 4; tn++) {
        int col = n0 + wn + tn * 16 + l15;
        int row0 = m0 + wm + tm * 16 + quad * 4;
        float b = bias[col];
        union { u16 h[4]; uint2 u2; } o;
#pragma unroll
        for (int r = 0; r < 4; r++) o.h[r] = f2bf(acc[tm][tn][r] + b);
        *(uint2*)&vT[(size_t)col * S_LEN + row0] = o.u2;
      }
  }
}

// ---------- attention: 32x32x16 MFMA, 32q waves, gl16 dbuf, 1 barrier/iter ----------
// 256 thr = 4 waves = {2 qsub(32q)} x {2 tsub(64t as 2 independent 32-t tiles)};
// t-tile 128/iter, 16 iters. Sᵀ = K·Qᵀ (C col = q = l31 — r5/r6-verified);
// P C->A via wave-private swizzled strip; partials combined via LDS atomics.
__global__ __launch_bounds__(256, 2) void attn_k(
    const u16* __restrict__ qb, const u16* __restrict__ kb,
    const u16* __restrict__ vT, u16* __restrict__ conc) {
  const int h = blockIdx.y, qblk = blockIdx.x * 64;
  const int tid = threadIdx.x;
  const int w = tid >> 6, lane = tid & 63, l31 = lane & 31, h5 = lane >> 5;
  const int qsub = w & 1, tsub = w >> 1;
  const int q0 = qblk + qsub * 32;

  // u16: K[2buf][8192] @0 (32KB), V[2buf][8192] @16384 (32KB), P[4][2048] @32768 (16KB) = 80KB
  __shared__ __align__(16) u16 smem[40960];
  u16* Pw = smem + 32768 + w * 2048;  // strip [32 q][8 chunks of 8t], slot = cs ^ (q&7)

  const u16* kbase = kb + (size_t)h * 64;
  const u16* vbase = vT + (size_t)(h * 64) * S_LEN;

  // Q B-frags: B[k=dk][n=q]; k = kI*16 + h5*8 + j (r5/r6-verified layout)
  bf16x8 qf[4];
#pragma unroll
  for (int kI = 0; kI < 4; kI++)
    qf[kI] = *(const bf16x8*)&qb[(size_t)(q0 + l31) * D_MODEL + h * 64 + kI * 16 + h5 * 8];

  // staging roles: waves 0,1 stage K (1024 chunks), waves 2,3 stage V (1024 chunks)
  const bool isK = (w < 2);
  const int pb = (isK ? w : (w - 2)) * 512;

  f32x16 oacc[2] = {};
  float lsum = 0.f;

  // preload it=0 into buf0
#pragma unroll
  for (int e = 0; e < 8; e++) {
    int p = pb + e * 64 + lane;
    if (isK) {
      int r = p >> 3, g = (p & 7) ^ (r & 7);
      gl16(kbase + (size_t)r * D_MODEL + g * 8, smem + (pb + e * 64) * 8);
    } else {
      int dv = p >> 4, g = (p & 15) ^ (dv & 15);
      gl16(vbase + (size_t)dv * S_LEN + g * 8, smem + 16384 + (pb + e * 64) * 8);
    }
  }

  for (int it = 0; it < 16; it++) {
    __syncthreads();
    if (it < 15) {  // prefetch next tile; stays in flight across this tile's compute
      const int t0n = (it + 1) * 128;
      const int nb = (it + 1) & 1;
#pragma unroll
      for (int e = 0; e < 8; e++) {
        int p = pb + e * 64 + lane;
        if (isK) {
          int r = p >> 3, g = (p & 7) ^ (r & 7);
          gl16(kbase + (size_t)(t0n + r) * D_MODEL + g * 8,
               smem + nb * 8192 + (pb + e * 64) * 8);
        } else {
          int dv = p >> 4, g = (p & 15) ^ (dv & 15);
          gl16(vbase + (size_t)dv * S_LEN + t0n + g * 8,
               smem + 16384 + nb * 8192 + (pb + e * 64) * 8);
        }
      }
    }
    const u16* Kc = smem + (it & 1) * 8192;
    const u16* Vc = smem + 16384 + (it & 1) * 8192;

    // Sᵀ: two independent 4-deep chains (wave's two 32-t tiles)
    f32x16 sacc[2] = {};
    {
      const int r0 = tsub * 64 + l31, r1 = r0 + 32;
#pragma unroll
      for (int kI = 0; kI < 4; kI++) {
        const int slot = ((kI * 2 + h5) ^ (l31 & 7)) * 8;
        bf16x8 ka0 = *(const bf16x8*)&Kc[r0 * 64 + slot];
        bf16x8 ka1 = *(const bf16x8*)&Kc[r1 * 64 + slot];
        sacc[0] = __builtin_amdgcn_mfma_f32_32x32x16_bf16(ka0, qf[kI], sacc[0], 0, 0, 0);
        sacc[1] = __builtin_amdgcn_mfma_f32_32x32x16_bf16(ka1, qf[kI], sacc[1], 0, 0, 0);
      }
    }

    // p = 2^s (log2e folded into q); C row t = (reg&3)+8*(reg>>2)+4*h5, col q = l31.
    // chunk cs = T*4+g holds t in [8cs, 8cs+8) of the wave's 64-t strip.
#pragma unroll
    for (int T = 0; T < 2; T++)
#pragma unroll
      for (int g = 0; g < 4; g++) {
        float p0 = exp2f(sacc[T][4 * g + 0]);
        float p1 = exp2f(sacc[T][4 * g + 1]);
        float p2 = exp2f(sacc[T][4 * g + 2]);
        float p3 = exp2f(sacc[T][4 * g + 3]);
        lsum += (p0 + p1) + (p2 + p3);
        uint2 pw2; pw2.x = pkbf2(p0, p1); pw2.y = pkbf2(p2, p3);
        int cs = T * 4 + g;
        *(uint2*)&Pw[l31 * 64 + ((cs ^ (l31 & 7)) * 8) + h5 * 4] = pw2;
      }

    // O += P·V : A = P[q][t] (own strip), B = Vᵀ rows; 2 independent dv-chains
#pragma unroll
    for (int kI = 0; kI < 4; kI++) {
      bf16x8 pa = *(const bf16x8*)&Pw[l31 * 64 + (((kI * 2 + h5) ^ (l31 & 7)) * 8)];
#pragma unroll
      for (int d = 0; d < 2; d++) {
        int dv = d * 32 + l31;
        int g = tsub * 8 + kI * 2 + h5;  // chunk within the 128-t V row
        bf16x8 vb = *(const bf16x8*)&Vc[dv * 128 + ((g ^ (dv & 15)) * 8)];
        oacc[d] = __builtin_amdgcn_mfma_f32_32x32x16_bf16(pa, vb, oacc[d], 0, 0, 0);
      }
    }
  }
  __syncthreads();  // all waves done with K/V buffers before overlay

  // combine the 4 waves' partials via LDS atomics (overlay on K region)
  float* Of = (float*)smem;   // [64 q][64 dv] = 16KB
  float* lf = Of + 4096;      // [64 q]
  for (int j = tid; j < 4160; j += 256) Of[j] = 0.f;
  __syncthreads();
#pragma unroll
  for (int d = 0; d < 2; d++)
#pragma unroll
    for (int reg = 0; reg < 16; reg++) {
      int qq = qsub * 32 + (reg & 3) + 8 * (reg >> 2) + 4 * h5;
      atomicAdd(&Of[qq * 64 + d * 32 + l31], oacc[d][reg]);
    }
  atomicAdd(&lf[qsub * 32 + l31], lsum);
  __syncthreads();

  const int q = tid >> 2, dvb = (tid & 3) * 16;
  float li = 1.0f / lf[q];
  const float* src = &Of[q * 64 + dvb];
  union { u16 hh[8]; uint4 u4; } o;
#pragma unroll
  for (int j = 0; j < 8; j++) o.hh[j] = f2bf(src[j] * li);
  *(uint4*)&conc[(size_t)(qblk + q) * D_MODEL + h * 64 + dvb] = o.u4;
#pragma unroll
  for (int j = 0; j < 8; j++) o.hh[j] = f2bf(src[8 + j] * li);
  *(uint4*)&conc[(size_t)(qblk + q) * D_MODEL + h * 64 + dvb + 8] = o.u4;
}

// ---------- output GEMM: 64x64 tile, BK=64, async dbuf, 1 barrier/iter ----------
__global__ __launch_bounds__(256, 4) void out_gemm_k(
    const u16* __restrict__ A, const u16* __restrict__ Bt,
    const float* __restrict__ bias, float* __restrict__ out) {
  const int n0 = blockIdx.x * 64, m0 = blockIdx.y * 64;
  __shared__ __align__(16) u16 smem[4 * 4096];
  const int tid = threadIdx.x;
  const int w = tid >> 6, lane = tid & 63, quad = lane >> 4, l15 = lane & 15;
  const int wm = (w >> 1) * 32, wn = (w & 1) * 32;
  const int pb = w * 128;

  f32x4 acc[2][2] = {};
  {
    u16* As = smem; u16* Bs = smem + 8192;
#pragma unroll
    for (int e = 0; e < 2; e++) {
      int p = pb + e * 64 + lane;
      int r = p >> 3, cg = (p & 7) ^ (r & 7);
      gl16(&A[(size_t)(m0 + r) * D_MODEL + cg * 8], As + (pb + e * 64) * 8);
      gl16(&Bt[(size_t)(n0 + r) * D_MODEL + cg * 8], Bs + (pb + e * 64) * 8);
    }
  }
  for (int it = 0; it < 16; it++) {
    __syncthreads();
    if (it < 15) {
      const int k0 = (it + 1) * 64;
      u16* As = smem + ((it + 1) & 1) * 4096;
      u16* Bs = smem + 8192 + ((it + 1) & 1) * 4096;
#pragma unroll
      for (int e = 0; e < 2; e++) {
        int p = pb + e * 64 + lane;
        int r = p >> 3, cg = (p & 7) ^ (r & 7);
        gl16(&A[(size_t)(m0 + r) * D_MODEL + k0 + cg * 8], As + (pb + e * 64) * 8);
        gl16(&Bt[(size_t)(n0 + r) * D_MODEL + k0 + cg * 8], Bs + (pb + e * 64) * 8);
      }
    }
    const u16* As = smem + (it & 1) * 4096;
    const u16* Bs = smem + 8192 + (it & 1) * 4096;
#pragma unroll
    for (int kc = 0; kc < 2; kc++) {
      const int c = kc * 4 + quad;
      bf16x8 af[2], bfr[2];
#pragma unroll
      for (int t = 0; t < 2; t++) {
        int ma = wm + t * 16 + l15, na = wn + t * 16 + l15;
        af[t] = *(const bf16x8*)&As[(ma * 8 + (c ^ (ma & 7))) * 8];
        bfr[t] = *(const bf16x8*)&Bs[(na * 8 + (c ^ (na & 7))) * 8];
      }
#pragma unroll
      for (int tm = 0; tm < 2; tm++)
#pragma unroll
        for (int tn = 0; tn < 2; tn++)
          acc[tm][tn] = __builtin_amdgcn_mfma_f32_16x16x32_bf16(af[tm], bfr[tn], acc[tm][tn], 0, 0, 0);
    }
  }
#pragma unroll
  for (int tm = 0; tm < 2; tm++)
#pragma unroll
    for (int tn = 0; tn < 2; tn++)
#pragma unroll
      for (int r = 0; r < 4; r++) {
        int row = m0 + wm + tm * 16 + quad * 4 + r;
        int col = n0 + wn + tn * 16 + l15;
        out[(size_t)row * D_MODEL + col] = acc[tm][tn][r] + bias[col];
      }
}

extern "C" void kernel_launch(void* const* d_in, const int* in_sizes, int n_in,
                              void* d_out, int out_size, void* d_ws, size_t ws_size,
                              hipStream_t stream) {
  const float* Q  = (const float*)d_in[0];
  const float* K  = (const float*)d_in[1];
  const float* V  = (const float*)d_in[2];
  const float* Wq = (const float*)d_in[3];
  const float* bq = (const float*)d_in[4];
  const float* Wk = (const float*)d_in[5];
  const float* bk = (const float*)d_in[6];
  const float* Wv = (const float*)d_in[7];
  const float* bv = (const float*)d_in[8];
  const float* Wo = (const float*)d_in[9];
  const float* bo = (const float*)d_in[10];
  float* out = (float*)d_out;

  u16* ws = (u16*)d_ws;
  u16* QKVb = ws;                                   // 3*S*D
  u16* Wqt  = QKVb + (size_t)3 * S_LEN * D_MODEL;   // D*D each
  u16* Wkt  = Wqt + (size_t)D_MODEL * D_MODEL;
  u16* Wvt  = Wkt + (size_t)D_MODEL * D_MODEL;
  u16* Wot  = Wvt + (size_t)D_MODEL * D_MODEL;
  u16* qbuf = Wot + (size_t)D_MODEL * D_MODEL;      // S*D
  u16* kbuf = qbuf + (size_t)S_LEN * D_MODEL;       // S*D
  u16* vTb  = kbuf + (size_t)S_LEN * D_MODEL;       // D*S
  u16* conc = vTb + (size_t)S_LEN * D_MODEL;        // S*D

  prep_k<<<dim3(10240), 256, 0, stream>>>(Q, K, V, Wq, Wk, Wv, Wo,
                                          QKVb, Wqt, Wkt, Wvt, Wot);
  proj_gemm_k<<<dim3(S_LEN / 128, D_MODEL / 128, 3), 256, 0, stream>>>(
      QKVb, Wqt, Wkt, Wvt, bq, bk, bv, qbuf, kbuf, vTb);
  attn_k<<<dim3(S_LEN / 64, NH), 256, 0, stream>>>(qbuf, kbuf, vTb, conc);
  out_gemm_k<<<dim3(D_MODEL / 64, S_LEN / 64), 256, 0, stream>>>(conc, Wot, bo, out);
}